// Round 8
// baseline (618.842 us; speedup 1.0000x reference)
//
#include <hip/hip_runtime.h>
#include <math.h>

typedef __bf16 bf16;
typedef __bf16 bf16x4 __attribute__((ext_vector_type(4)));
typedef __bf16 bf16x8 __attribute__((ext_vector_type(8)));
typedef float  f32x4  __attribute__((ext_vector_type(4)));

#define B_   4
#define N_   2048
#define C_   768
#define H_   12
#define T_   8192      // B_*N_
#define HID_ 3072

#if __has_builtin(__builtin_amdgcn_exp2f)
#define EXP2F __builtin_amdgcn_exp2f
#else
#define EXP2F exp2f
#endif
#if __has_builtin(__builtin_amdgcn_rcpf)
#define RCPF __builtin_amdgcn_rcpf
#else
#define RCPF(x) (1.0f / (x))
#endif

// async global->LDS, 16 B per lane. LDS dest must be wave-uniform base + lane*16.
typedef const __attribute__((address_space(1))) unsigned int* as1_u32;
typedef __attribute__((address_space(3))) unsigned int* as3_u32;
__device__ __forceinline__ void gl_lds16(const void* g, void* l) {
    __builtin_amdgcn_global_load_lds((as1_u32)g, (as3_u32)l, 16, 0, 0);
}

// ---------------------------------------------------------------------------
// LayerNorm: one wave per row (C=768 = 12*64). f32 in, fp32 stats, bf16 out.
// ---------------------------------------------------------------------------
__global__ __launch_bounds__(256)
void ln_kernel(const float* __restrict__ inp, const float* __restrict__ g,
               const float* __restrict__ bsh, bf16* __restrict__ out)
{
    int wave = threadIdx.x >> 6, lane = threadIdx.x & 63;
    long long row = (long long)blockIdx.x * 4 + wave;
    const float* p = inp + row * C_;
    float v[12];
    #pragma unroll
    for (int i = 0; i < 12; i++) v[i] = p[i * 64 + lane];
    float s = 0.f, s2 = 0.f;
    #pragma unroll
    for (int i = 0; i < 12; i++) { s += v[i]; s2 += v[i] * v[i]; }
    #pragma unroll
    for (int m = 1; m < 64; m <<= 1) {
        s  += __shfl_xor(s,  m, 64);
        s2 += __shfl_xor(s2, m, 64);
    }
    float mu  = s  * (1.f / C_);
    float var = s2 * (1.f / C_) - mu * mu;
    float rs  = rsqrtf(var + 1e-5f);
    bf16* o = out + row * C_;
    #pragma unroll
    for (int i = 0; i < 12; i++) {
        int c = i * 64 + lane;
        o[c] = (bf16)(((v[i] - mu) * rs) * g[c] + bsh[c]);
    }
}

// ---------------------------------------------------------------------------
// GEMM (wide-N): C = A(bf16) @ Bw(f32)^T. 128x128 tile, BK=32, double-buffered,
// one barrier/iter, A via async DMA, B prefetched in regs across compute.
// MODE 2: out bf16 = gelu_tanh(acc + bias)   (fc1)
// MODE 3: qkv split: cols [0,1536) -> QK bf16; cols [1536,2304) -> V^T
// ---------------------------------------------------------------------------
template<int MODE>
__global__ __launch_bounds__(256)
void gemm_bt(const bf16* __restrict__ A, const float* __restrict__ Bw,
             int M, int N, int K,
             const float* __restrict__ bias,
             void* out, bf16* out2)
{
    __shared__ bf16 At[2][128 * 32];
    __shared__ bf16 Bt[2][128 * 32];
    int tid  = threadIdx.x;
    int lane = tid & 63, wave = tid >> 6;
    int quad = lane >> 4, l15 = lane & 15;
    int bm = blockIdx.x, bn = blockIdx.y;
    int wm = wave >> 1, wn = wave & 1;
    int swz = (l15 >> 1) & 3;

    f32x4 acc[4][4];
    f32x4 zero = {0.f, 0.f, 0.f, 0.f};
    #pragma unroll
    for (int mt = 0; mt < 4; mt++)
        #pragma unroll
        for (int nt = 0; nt < 4; nt++) acc[mt][nt] = zero;

    int arow = tid >> 2;                              // 0..63
    int aq   = (tid & 3) ^ ((arow >> 1) & 3);         // permuted k-chunk
    const bf16*  ag0 = A  + (size_t)(bm * 128 + arow) * K + aq * 8;
    const float* bg0 = Bw + (size_t)(bn * 128 + arow) * K + aq * 8;

    // stage tile 0
    gl_lds16(ag0,                    &At[0][tid * 8]);
    gl_lds16(ag0 + (size_t)64 * K,   &At[0][2048 + tid * 8]);
    {
        f32x4 b0a = *(const f32x4*)(bg0);
        f32x4 b0b = *(const f32x4*)(bg0 + 4);
        f32x4 b1a = *(const f32x4*)(bg0 + (size_t)64 * K);
        f32x4 b1b = *(const f32x4*)(bg0 + (size_t)64 * K + 4);
        bf16x8 b0, b1;
        #pragma unroll
        for (int j = 0; j < 4; j++) {
            b0[j] = (bf16)b0a[j]; b0[4 + j] = (bf16)b0b[j];
            b1[j] = (bf16)b1a[j]; b1[4 + j] = (bf16)b1b[j];
        }
        *(bf16x8*)(&Bt[0][tid * 8])        = b0;
        *(bf16x8*)(&Bt[0][2048 + tid * 8]) = b1;
    }
    __syncthreads();

    int nk = K >> 5;
    f32x4 pba, pbb, pca, pcb;     // B prefetch registers
    for (int kt = 0; kt < nk; kt++) {
        int cur = kt & 1, nxt = cur ^ 1;
        if (kt + 1 < nk) {
            const bf16*  ag = ag0 + (size_t)(kt + 1) * 32;
            const float* bg = bg0 + (size_t)(kt + 1) * 32;
            gl_lds16(ag,                  &At[nxt][tid * 8]);
            gl_lds16(ag + (size_t)64 * K, &At[nxt][2048 + tid * 8]);
            pba = *(const f32x4*)(bg);
            pbb = *(const f32x4*)(bg + 4);
            pca = *(const f32x4*)(bg + (size_t)64 * K);
            pcb = *(const f32x4*)(bg + (size_t)64 * K + 4);
        }

        bf16x8 af[4], bfr[4];
        #pragma unroll
        for (int mt = 0; mt < 4; mt++)
            af[mt] = *(const bf16x8*)(&At[cur][wm * 2048 + (mt * 16 + l15) * 32 + ((quad ^ swz) << 3)]);
        #pragma unroll
        for (int nt = 0; nt < 4; nt++)
            bfr[nt] = *(const bf16x8*)(&Bt[cur][wn * 2048 + (nt * 16 + l15) * 32 + ((quad ^ swz) << 3)]);
        #pragma unroll
        for (int mt = 0; mt < 4; mt++)
            #pragma unroll
            for (int nt = 0; nt < 4; nt++)
                acc[mt][nt] = __builtin_amdgcn_mfma_f32_16x16x32_bf16(
                    af[mt], bfr[nt], acc[mt][nt], 0, 0, 0);

        if (kt + 1 < nk) {
            bf16x8 b0, b1;
            #pragma unroll
            for (int j = 0; j < 4; j++) {
                b0[j] = (bf16)pba[j]; b0[4 + j] = (bf16)pbb[j];
                b1[j] = (bf16)pca[j]; b1[4 + j] = (bf16)pcb[j];
            }
            *(bf16x8*)(&Bt[nxt][tid * 8])        = b0;
            *(bf16x8*)(&Bt[nxt][2048 + tid * 8]) = b1;
        }
        __syncthreads();
    }

    if (MODE == 3) {
        if (bn < 12) {
            #pragma unroll
            for (int nt = 0; nt < 4; nt++) {
                int col = bn * 128 + wn * 64 + nt * 16 + l15;
                #pragma unroll
                for (int mt = 0; mt < 4; mt++)
                    #pragma unroll
                    for (int r = 0; r < 4; r++) {
                        int row = bm * 128 + wm * 64 + mt * 16 + quad * 4 + r;
                        ((bf16*)out)[(size_t)row * 1536 + col] = (bf16)acc[mt][nt][r];
                    }
            }
        } else {
            int b = bm >> 4;
            #pragma unroll
            for (int nt = 0; nt < 4; nt++) {
                int vcol = bn * 128 - 1536 + wn * 64 + nt * 16 + l15;  // 0..767
                int h = vcol >> 6, d = vcol & 63;
                size_t rowbase = ((size_t)(b * H_ + h) * 64 + d) * N_;
                #pragma unroll
                for (int mt = 0; mt < 4; mt++) {
                    int n0 = (bm & 15) * 128 + wm * 64 + mt * 16 + quad * 4;
                    bf16x4 pv;
                    #pragma unroll
                    for (int r = 0; r < 4; r++) pv[r] = (bf16)acc[mt][nt][r];
                    *(bf16x4*)(&out2[rowbase + n0]) = pv;
                }
            }
        }
    } else {
        #pragma unroll
        for (int nt = 0; nt < 4; nt++) {
            int col = bn * 128 + wn * 64 + nt * 16 + l15;
            float bv = bias[col];
            #pragma unroll
            for (int mt = 0; mt < 4; mt++) {
                #pragma unroll
                for (int r = 0; r < 4; r++) {
                    int row = bm * 128 + wm * 64 + mt * 16 + quad * 4 + r;
                    size_t idx = (size_t)row * N + col;
                    float v = acc[mt][nt][r] + bv;
                    // tanh-GELU (max abs err ~3e-3 vs exact erf form)
                    float t = v * v;
                    float u = v * fmaf(t, 0.0356774081f, 0.7978845608f);
                    float e = EXP2F(u * 2.8853900818f);     // e^{2u}
                    float ge = v - v * RCPF(e + 1.f);
                    ((bf16*)out)[idx] = (bf16)ge;
                }
            }
        }
    }
}

// ---------------------------------------------------------------------------
// GEMM (narrow-N, N=768): 64x256 tile, BK=32 — maximizes A-panel reuse (A-L3
// traffic /4 vs 64-wide tiles) for proj (K=768) and fc2 (K=3072).
// Grid (M/64, 3) = 384 blocks. Double-buffered, reg-prefetch pipeline.
// out f32 = acc + bias + resid (resid may alias out; per-element
// load-before-store by owner thread).
// ---------------------------------------------------------------------------
__global__ __launch_bounds__(256)
void gemm_n256(const bf16* __restrict__ A, const float* __restrict__ Bw,
               int K, const float* __restrict__ bias,
               const float* resid_f, float* out)
{
    __shared__ bf16 At[2][64 * 32];      // 4 KB each
    __shared__ bf16 Bt[2][256 * 32];     // 16 KB each
    int tid  = threadIdx.x;
    int lane = tid & 63, wave = tid >> 6;
    int quad = lane >> 4, l15 = lane & 15;
    int bm = blockIdx.x, bn = blockIdx.y;
    int wm = wave >> 1, wn = wave & 1;   // wave tile: rows wm*32+, cols wn*128+
    int swz = (l15 >> 1) & 3;

    f32x4 acc[2][8];
    f32x4 zero = {0.f, 0.f, 0.f, 0.f};
    #pragma unroll
    for (int mt = 0; mt < 2; mt++)
        #pragma unroll
        for (int nt = 0; nt < 8; nt++) acc[mt][nt] = zero;

    int arow = tid >> 2;                              // 0..63
    int aq   = (tid & 3) ^ ((arow >> 1) & 3);         // permuted k-chunk
    const bf16*  ag0 = A  + (size_t)(bm * 64 + arow) * K + aq * 8;
    int bperm = (tid >> 1) & 3;
    const float* bg0 = Bw + (size_t)(bn * 256 + tid) * K;   // one B-row/thread

    // stage tile 0
    gl_lds16(ag0, &At[0][tid * 8]);
    {
        #pragma unroll
        for (int c = 0; c < 4; c++) {
            f32x4 xa = *(const f32x4*)(bg0 + c * 8);
            f32x4 xb = *(const f32x4*)(bg0 + c * 8 + 4);
            bf16x8 b;
            #pragma unroll
            for (int j = 0; j < 4; j++) { b[j] = (bf16)xa[j]; b[4 + j] = (bf16)xb[j]; }
            *(bf16x8*)(&Bt[0][tid * 32 + ((c ^ bperm) << 3)]) = b;
        }
    }
    __syncthreads();

    int nk = K >> 5;
    f32x4 pb[8];
    for (int kt = 0; kt < nk; kt++) {
        int cur = kt & 1, nxt = cur ^ 1;
        if (kt + 1 < nk) {
            gl_lds16(ag0 + (size_t)(kt + 1) * 32, &At[nxt][tid * 8]);
            const float* bg = bg0 + (size_t)(kt + 1) * 32;
            #pragma unroll
            for (int c = 0; c < 4; c++) {
                pb[2 * c]     = *(const f32x4*)(bg + c * 8);
                pb[2 * c + 1] = *(const f32x4*)(bg + c * 8 + 4);
            }
        }

        bf16x8 af[2], bfr[8];
        #pragma unroll
        for (int mt = 0; mt < 2; mt++)
            af[mt] = *(const bf16x8*)(&At[cur][(wm * 32 + mt * 16 + l15) * 32 + ((quad ^ swz) << 3)]);
        #pragma unroll
        for (int nt = 0; nt < 8; nt++)
            bfr[nt] = *(const bf16x8*)(&Bt[cur][(wn * 128 + nt * 16 + l15) * 32 + ((quad ^ swz) << 3)]);
        #pragma unroll
        for (int mt = 0; mt < 2; mt++)
            #pragma unroll
            for (int nt = 0; nt < 8; nt++)
                acc[mt][nt] = __builtin_amdgcn_mfma_f32_16x16x32_bf16(
                    af[mt], bfr[nt], acc[mt][nt], 0, 0, 0);

        if (kt + 1 < nk) {
            #pragma unroll
            for (int c = 0; c < 4; c++) {
                bf16x8 b;
                #pragma unroll
                for (int j = 0; j < 4; j++) {
                    b[j] = (bf16)pb[2 * c][j]; b[4 + j] = (bf16)pb[2 * c + 1][j];
                }
                *(bf16x8*)(&Bt[nxt][tid * 32 + ((c ^ bperm) << 3)]) = b;
            }
        }
        __syncthreads();
    }

    #pragma unroll
    for (int nt = 0; nt < 8; nt++) {
        int col = bn * 256 + wn * 128 + nt * 16 + l15;
        float bv = bias[col];
        #pragma unroll
        for (int mt = 0; mt < 2; mt++) {
            #pragma unroll
            for (int r = 0; r < 4; r++) {
                int row = bm * 64 + wm * 32 + mt * 16 + quad * 4 + r;
                size_t idx = (size_t)row * C_ + col;
                out[idx] = acc[mt][nt][r] + bv + resid_f[idx];
            }
        }
    }
}

// ---------------------------------------------------------------------------
// Flash attention, transposed formulation. Round-8 trims: K-frag reads hoisted
// out of the qi loop; exp folded to a single FMA+v_exp (base-2 stats); oacc/l
// rescale skipped via __any when the running max didn't increase.
// ---------------------------------------------------------------------------
__global__ __launch_bounds__(256)
void attn_kernel(const bf16* __restrict__ qk, const bf16* __restrict__ vt,
                 bf16* __restrict__ o)
{
    __shared__ bf16 Kt[2][64 * 64];     // [key][d], swizzled
    __shared__ bf16 Vt[2][64 * 64];     // [d][key], swizzled
    __shared__ bf16 Pt[4][2][16 * 64];  // per-wave, per-qtile [query][key], swizzled

    const float SC = 0.18033688011112042f;   // 0.125 * log2(e)

    int tid = threadIdx.x, lane = tid & 63, wave = tid >> 6;
    int quad = lane >> 4, l15 = lane & 15;
    int swz = (l15 & 7);                // read-side swizzle key
    int blk = blockIdx.x;
    int qb = blk & 15;      // 16 query blocks of 128
    int bh = blk >> 4;      // 0..47
    int b = bh / H_, h = bh % H_;

    const bf16* qbase = qk + (size_t)(b * N_) * 1536 + h * 64;
    const bf16* kbase = qbase + 768;
    const bf16* vtb   = vt + (size_t)(bh * 64) * N_;

    bf16x8 qf[2][2];
    #pragma unroll
    for (int qi = 0; qi < 2; qi++) {
        int q = qb * 128 + wave * 32 + qi * 16 + l15;
        const bf16* qp = qbase + (size_t)q * 1536 + quad * 8;
        qf[qi][0] = *(const bf16x8*)(qp);
        qf[qi][1] = *(const bf16x8*)(qp + 32);
    }

    int srow = tid >> 3, schk = tid & 7;
    int soA = srow * 64 + ((schk ^ (srow & 7)) << 3);
    int soB = (srow + 32) * 64 + ((schk ^ (srow & 7)) << 3);

    bf16x8 kr0, kr1, vr0, vr1;
    const bf16* kg0 = kbase + (size_t)srow * 1536 + schk * 8;
    const bf16* vg0 = vtb + (size_t)srow * N_ + schk * 8;

    {
        kr0 = *(const bf16x8*)(kg0);
        kr1 = *(const bf16x8*)(kg0 + (size_t)32 * 1536);
        vr0 = *(const bf16x8*)(vg0);
        vr1 = *(const bf16x8*)(vg0 + (size_t)32 * N_);
        *(bf16x8*)(&Kt[0][soA]) = kr0;  *(bf16x8*)(&Kt[0][soB]) = kr1;
        *(bf16x8*)(&Vt[0][soA]) = vr0;  *(bf16x8*)(&Vt[0][soB]) = vr1;
    }
    __syncthreads();

    f32x4 oacc[2][4];
    f32x4 zero = {0.f, 0.f, 0.f, 0.f};
    #pragma unroll
    for (int qi = 0; qi < 2; qi++)
        #pragma unroll
        for (int nt = 0; nt < 4; nt++) oacc[qi][nt] = zero;
    float mrun[2] = {-1e30f, -1e30f}, lrun[2] = {0.f, 0.f};

    for (int kt = 0; kt < 32; kt++) {
        int cur = kt & 1;
        if (kt < 31) {
            const bf16* kg = kg0 + (size_t)(kt + 1) * 64 * 1536;
            const bf16* vg = vg0 + (size_t)(kt + 1) * 64;
            kr0 = *(const bf16x8*)(kg);
            kr1 = *(const bf16x8*)(kg + (size_t)32 * 1536);
            vr0 = *(const bf16x8*)(vg);
            vr1 = *(const bf16x8*)(vg + (size_t)32 * N_);
        }
        const bf16* KtC = &Kt[cur][0];
        const bf16* VtC = &Vt[cur][0];

        // ---- S^T = K Q^T for BOTH q-tiles; K-frags read once ----
        f32x4 s[2][4];
        #pragma unroll
        for (int nt = 0; nt < 4; nt++) {
            const bf16* krow = KtC + (nt * 16 + l15) * 64;
            bf16x8 ka0 = *(const bf16x8*)(krow + ((quad ^ swz) << 3));
            bf16x8 ka1 = *(const bf16x8*)(krow + (((4 + quad) ^ swz) << 3));
            f32x4 sv0 = zero, sv1 = zero;
            sv0 = __builtin_amdgcn_mfma_f32_16x16x32_bf16(ka0, qf[0][0], sv0, 0, 0, 0);
            sv0 = __builtin_amdgcn_mfma_f32_16x16x32_bf16(ka1, qf[0][1], sv0, 0, 0, 0);
            sv1 = __builtin_amdgcn_mfma_f32_16x16x32_bf16(ka0, qf[1][0], sv1, 0, 0, 0);
            sv1 = __builtin_amdgcn_mfma_f32_16x16x32_bf16(ka1, qf[1][1], sv1, 0, 0, 0);
            s[0][nt] = sv0;
            s[1][nt] = sv1;
        }

        #pragma unroll
        for (int qi = 0; qi < 2; qi++) {
            float mx = -1e30f;
            #pragma unroll
            for (int nt = 0; nt < 4; nt++)
                #pragma unroll
                for (int r = 0; r < 4; r++) mx = fmaxf(mx, s[qi][nt][r]);
            mx = fmaxf(mx, __shfl_xor(mx, 16, 64));
            mx = fmaxf(mx, __shfl_xor(mx, 32, 64));
            float m2 = mx * SC;                       // base-2 units
            if (__any(m2 > mrun[qi])) {
                float mnew = fmaxf(mrun[qi], m2);
                float al = EXP2F(mrun[qi] - mnew);
                mrun[qi] = mnew;
                lrun[qi] *= al;
                #pragma unroll
                for (int nt = 0; nt < 4; nt++) oacc[qi][nt] *= al;
            }
            float mcur = mrun[qi];
            float ps = 0.f;
            #pragma unroll
            for (int nt = 0; nt < 4; nt++)
                #pragma unroll
                for (int r = 0; r < 4; r++) {
                    float pv = EXP2F(fmaf(s[qi][nt][r], SC, -mcur));
                    s[qi][nt][r] = pv;
                    ps += pv;
                }
            ps += __shfl_xor(ps, 16, 64);
            ps += __shfl_xor(ps, 32, 64);
            lrun[qi] += ps;
            bf16* pw = &Pt[wave][qi][0];
            #pragma unroll
            for (int nt = 0; nt < 4; nt++) {
                bf16x4 pk;
                #pragma unroll
                for (int r = 0; r < 4; r++) pk[r] = (bf16)s[qi][nt][r];
                int ofs = l15 * 64 + (((nt * 2 + (quad >> 1)) ^ swz) << 3) + ((quad & 1) << 2);
                *(bf16x4*)(&pw[ofs]) = pk;
            }
        }

        // ---- O^T += V^T P^T ----
        #pragma unroll
        for (int kc = 0; kc < 2; kc++) {
            int pofs = l15 * 64 + (((kc * 4 + quad) ^ swz) << 3);
            bf16x8 pb0 = *(const bf16x8*)(&Pt[wave][0][pofs]);
            bf16x8 pb1 = *(const bf16x8*)(&Pt[wave][1][pofs]);
            #pragma unroll
            for (int nt = 0; nt < 4; nt++) {
                bf16x8 va = *(const bf16x8*)(VtC + (nt * 16 + l15) * 64 +
                                             (((kc * 4 + quad) ^ swz) << 3));
                oacc[0][nt] = __builtin_amdgcn_mfma_f32_16x16x32_bf16(va, pb0, oacc[0][nt], 0, 0, 0);
                oacc[1][nt] = __builtin_amdgcn_mfma_f32_16x16x32_bf16(va, pb1, oacc[1][nt], 0, 0, 0);
            }
        }

        if (kt < 31) {
            int nxt = cur ^ 1;
            *(bf16x8*)(&Kt[nxt][soA]) = kr0;  *(bf16x8*)(&Kt[nxt][soB]) = kr1;
            *(bf16x8*)(&Vt[nxt][soA]) = vr0;  *(bf16x8*)(&Vt[nxt][soB]) = vr1;
        }
        __syncthreads();
    }

    #pragma unroll
    for (int qi = 0; qi < 2; qi++) {
        int q = qb * 128 + wave * 32 + qi * 16 + l15;
        float inv = 1.f / lrun[qi];
        bf16* ob = o + (size_t)(b * N_ + q) * C_ + h * 64 + quad * 4;
        #pragma unroll
        for (int nt = 0; nt < 4; nt++) {
            bf16x4 pk;
            #pragma unroll
            for (int r = 0; r < 4; r++) pk[r] = (bf16)(oacc[qi][nt][r] * inv);
            *(bf16x4*)(&ob[nt * 16]) = pk;
        }
    }
}

// ---------------------------------------------------------------------------
// Workspace (62.9 MB):
//   [0, 25165824)          QK [T,1536] bf16      (attention phase)
//   [25165824, 37748736)   V_T [48][64][2048] bf16
//   [0, 50331648)          gelu(fc1) [T,3072] bf16 (MLP phase, reuses above)
//   [50331648, 62914560)   R1: h / o / h2 [T,768] bf16
// Residual stream x1 lives f32 in d_out.
// ---------------------------------------------------------------------------
extern "C" void kernel_launch(void* const* d_in, const int* in_sizes, int n_in,
                              void* d_out, int out_size, void* d_ws, size_t ws_size,
                              hipStream_t stream)
{
    const float* x      = (const float*)d_in[0];
    const float* ln1_g  = (const float*)d_in[1];
    const float* ln1_b  = (const float*)d_in[2];
    const float* qkv_w  = (const float*)d_in[3];
    const float* proj_w = (const float*)d_in[4];
    const float* proj_b = (const float*)d_in[5];
    const float* ln2_g  = (const float*)d_in[6];
    const float* ln2_b  = (const float*)d_in[7];
    const float* fc1_w  = (const float*)d_in[8];
    const float* fc1_b  = (const float*)d_in[9];
    const float* fc2_w  = (const float*)d_in[10];
    const float* fc2_b  = (const float*)d_in[11];
    float* out = (float*)d_out;

    char* ws = (char*)d_ws;
    bf16* QK = (bf16*)ws;                                   // T x 1536
    bf16* VT = (bf16*)(ws + (size_t)T_ * 1536 * 2);         // 48 x 64 x 2048
    bf16* G  = (bf16*)ws;                                   // T x 3072 (MLP phase)
    bf16* R1 = (bf16*)(ws + (size_t)T_ * HID_ * 2);         // T x 768

    // 1. LN1: x (f32) -> h (R1, bf16)
    ln_kernel<<<T_ / 4, 256, 0, stream>>>(x, ln1_g, ln1_b, R1);
    // 2. qkv = h @ qkv_w^T -> QK [T,1536] + VT (transposed V)
    gemm_bt<3><<<dim3(T_ / 128, 2304 / 128), 256, 0, stream>>>(
        R1, qkv_w, T_, 2304, C_, nullptr, QK, VT);
    // 3. attention -> o (R1) [T,768] bf16
    attn_kernel<<<48 * 16, 256, 0, stream>>>(QK, VT, R1);
    // 4. x1 = x + o @ proj_w^T + proj_b -> d_out (f32)
    gemm_n256<<<dim3(T_ / 64, C_ / 256), 256, 0, stream>>>(
        R1, proj_w, C_, proj_b, x, out);
    // 5. LN2: x1 (f32) -> h2 (R1, bf16)
    ln_kernel<<<T_ / 4, 256, 0, stream>>>(out, ln2_g, ln2_b, R1);
    // 6. g1 = gelu(h2 @ fc1_w^T + fc1_b) -> G [T,3072] bf16
    gemm_bt<2><<<dim3(T_ / 128, HID_ / 128), 256, 0, stream>>>(
        R1, fc1_w, T_, HID_, C_, fc1_b, G, nullptr);
    // 7. out = x1 + g1 @ fc2_w^T + fc2_b -> d_out (in-place residual read, f32)
    gemm_n256<<<dim3(T_ / 64, C_ / 256), 256, 0, stream>>>(
        G, fc2_w, HID_, fc2_b, out, out);
}